// Round 7
// baseline (298.613 us; speedup 1.0000x reference)
//
#include <hip/hip_runtime.h>

typedef _Float16 h8 __attribute__((ext_vector_type(8)));
typedef _Float16 h4 __attribute__((ext_vector_type(4)));
typedef float f4 __attribute__((ext_vector_type(4)));

typedef __attribute__((address_space(1))) const void GV;
typedef __attribute__((address_space(3))) void SV;

__device__ __forceinline__ void async16(const void* g, void* s) {
  __builtin_amdgcn_global_load_lds((GV*)g, (SV*)s, 16, 0, 0);
}

// x: (4,4096,1024) fp32; w_qkv: (3072,1024) fp32 rows e=h*192+d*3+t;
// mem_kv: (2,16,4,64) fp32; mask: (4,4096) int32; out: (4,4096,1024) fp32.
//
// wh is PERMUTED during convert:
//   rows [0,2048):  [h][c]  c<64 -> k-row h*192+c*3+1 ; c>=64 -> v-row h*192+(c-64)*3+2
//   rows [2048,3072): [h][d] -> q-row h*192+d*3
// gemm n-tile bx<16 = head bx's full (k|v) -> ctx fused in epilogue,
// EK/V never hit HBM. q-tiles store P n-major (no write amplification;
// P is directly the attn A-fragment layout).

#define X4N 4194304   // 16777216/4

// ---------------- kernel 1: fp32 -> f16 convert; W rows permuted ----------
__global__ __launch_bounds__(256) void cvt_f16(const float4* __restrict__ x,
                                               const float4* __restrict__ w,
                                               h4* __restrict__ xh,
                                               h4* __restrict__ wh) {
  int i = blockIdx.x * 256 + threadIdx.x;
  if (i < X4N) {
    float4 v = x[i];
    h4 o = {(_Float16)v.x, (_Float16)v.y, (_Float16)v.z, (_Float16)v.w};
    xh[i] = o;
  } else {
    int j = i - X4N;                 // 0..786431
    int rp = j >> 8, kc = j & 255;   // dest row, k-chunk (4 floats)
    int sr;
    if (rp < 2048) {
      int h = rp >> 7, c = rp & 127;
      sr = h * 192 + ((c < 64) ? (c * 3 + 1) : ((c - 64) * 3 + 2));
    } else {
      int q = rp - 2048;
      sr = (q >> 6) * 192 + (q & 63) * 3;
    }
    float4 v = w[sr * 256 + kc];
    h4 o = {(_Float16)v.x, (_Float16)v.y, (_Float16)v.z, (_Float16)v.w};
    wh[rp * 256 + kc] = o;
  }
}

// ---------------- kernel 2: fused qkv GEMM + ctx-partial / P epilogue ----
// grid (24 n-tiles, 128 m-tiles). bx<16: kv-tile (head bx). bx>=16: q-tile.
// part layout per (bh, m-chunk): 4096 ctx[d][e] + 64 den[d] floats.
__global__ __launch_bounds__(256, 3) void gemm_fused(const _Float16* __restrict__ A,
                                                     const _Float16* __restrict__ W,
                                                     const int* __restrict__ mask,
                                                     _Float16* __restrict__ P,
                                                     float* __restrict__ part) {
  __shared__ _Float16 smem[128 * 128];  // 32 KB; first 16 KB = staging
  _Float16* const As = smem;
  _Float16* const Bs = smem + 4096;
  const int tid = threadIdx.x;
  const int lane = tid & 63, wid = tid >> 6;
  const int wm = wid & 1, wn = wid >> 1;
  const int l15 = lane & 15, quad = lane >> 4;
  const int m0 = blockIdx.y * 128;
  const int n0 = blockIdx.x * 128;

  const f4 z = {0.f, 0.f, 0.f, 0.f};
  f4 acc[4][4];
#pragma unroll
  for (int i = 0; i < 4; ++i)
#pragma unroll
    for (int j = 0; j < 4; ++j) acc[i][j] = z;

  for (int kt = 0; kt < 32; ++kt) {
    const int k0 = kt * 32;
#pragma unroll
    for (int it = 0; it < 2; ++it) {
      const int c = wid + it * 4;         // 8 chunks of 1KB per tile
      const int idx = c * 64 + lane;      // 0..511
      const int row = idx >> 2, cg = idx & 3;
      async16(A + ((size_t)(m0 + row) * 1024 + k0 + cg * 8), As + c * 512);
      async16(W + ((size_t)(n0 + row) * 1024 + k0 + cg * 8), Bs + c * 512);
    }
    __syncthreads();
    h8 af[4], bf[4];
#pragma unroll
    for (int i = 0; i < 4; ++i)
      af[i] = *(const h8*)&As[(wm * 64 + i * 16 + l15) * 32 + quad * 8];
#pragma unroll
    for (int j = 0; j < 4; ++j)
      bf[j] = *(const h8*)&Bs[(wn * 64 + j * 16 + l15) * 32 + quad * 8];
#pragma unroll
    for (int i = 0; i < 4; ++i)
#pragma unroll
      for (int j = 0; j < 4; ++j)
        acc[i][j] = __builtin_amdgcn_mfma_f32_16x16x32_f16(af[i], bf[j], acc[i][j], 0, 0, 0);
    __syncthreads();
  }

  if (n0 < 2048) {
    // ---- kv epilogue: exp(k)+mask, LDS round-trip, ctx partial via MFMA --
    const int h = n0 >> 7;
    const int b = m0 >> 12;
    const int lc = (m0 & 4095) >> 7;     // m-chunk within batch, 0..31
    const int bh = b * 16 + h;
    // write ek (cols 0..63) / v (cols 64..127) into XOR-swizzled LDS [c][128n]
#pragma unroll
    for (int i = 0; i < 4; ++i) {
      const int nb = wm * 64 + i * 16 + quad * 4;
#pragma unroll
      for (int j = 0; j < 4; ++j) {
        const int c = wn * 64 + j * 16 + l15;
        h4 o;
        if (wn == 0) {
#pragma unroll
          for (int r = 0; r < 4; ++r)
            o[r] = (_Float16)(mask[m0 + nb + r] ? __expf(acc[i][j][r]) : 0.f);
        } else {
#pragma unroll
          for (int r = 0; r < 4; ++r) o[r] = (_Float16)acc[i][j][r];
        }
        *(h4*)&smem[c * 128 + (nb ^ (l15 * 8))] = o;
      }
    }
    __syncthreads();
    // ctx[d][e] = sum_n ek[n][d] v[n][e]; wave w owns d-stripe [16w,16w+16)
    f4 cacc[5];
#pragma unroll
    for (int i = 0; i < 5; ++i) cacc[i] = z;
    h8 bones;
    {
      const _Float16 o1 = (l15 == 0) ? (_Float16)1.f : (_Float16)0.f;
#pragma unroll
      for (int j = 0; j < 8; ++j) bones[j] = o1;
    }
    const int ds = wid * 16;
#pragma unroll
    for (int ks = 0; ks < 4; ++ks) {
      const int nb2 = (ks * 32 + quad * 8) ^ (l15 * 8);
      h8 a = *(const h8*)&smem[(ds + l15) * 128 + nb2];
#pragma unroll
      for (int et = 0; et < 4; ++et) {
        h8 bv = *(const h8*)&smem[(64 + et * 16 + l15) * 128 + nb2];
        cacc[et] = __builtin_amdgcn_mfma_f32_16x16x32_f16(a, bv, cacc[et], 0, 0, 0);
      }
      cacc[4] = __builtin_amdgcn_mfma_f32_16x16x32_f16(a, bones, cacc[4], 0, 0, 0);
    }
    const size_t pb = ((size_t)bh * 32 + lc) * 4160;
    const int dw = ds + quad * 4;
#pragma unroll
    for (int et = 0; et < 4; ++et)
#pragma unroll
      for (int r = 0; r < 4; ++r)
        part[pb + (size_t)(dw + r) * 64 + et * 16 + l15] = cacc[et][r];
    if (l15 == 0) {
#pragma unroll
      for (int r = 0; r < 4; ++r) part[pb + 4096 + dw + r] = cacc[4][r];
    }
  } else {
    // ---- q epilogue: P = exp(q/8), n-major scalar stores (no write amp) --
#pragma unroll
    for (int i = 0; i < 4; ++i) {
      const int rg = m0 + wm * 64 + i * 16 + quad * 4;
#pragma unroll
      for (int j = 0; j < 4; ++j) {
        const int qc = (n0 - 2048) + wn * 64 + j * 16 + l15;  // = h*64+d
#pragma unroll
        for (int r = 0; r < 4; ++r)
          P[(size_t)(rg + r) * 1024 + qc] = (_Float16)__expf(acc[i][j][r] * 0.125f);
      }
    }
  }
}

// ---------------- kernel 3: reduce partials + memkv, store ctx^T ---------
// grid (64 bh, 16 d-slices). Thread (dl = tid>>6, e = tid&63) owns one (d,e).
// Chunk reads are wave-contiguous 256 B; den loads broadcast across e-lanes.
__global__ __launch_bounds__(256) void reduce_ctx(const float* __restrict__ part,
                                                  const float* __restrict__ memkv,
                                                  _Float16* __restrict__ ctxt) {
  const int bh = blockIdx.x;
  const int dsl = blockIdx.y;
  const int h = bh & 15;
  const int tid = threadIdx.x;
  const int dl = tid >> 6, e = tid & 63;
  const int d = dsl * 4 + dl;
  const size_t pb = (size_t)bh * 32 * 4160;

  float den = 0.f;
#pragma unroll 8
  for (int c = 0; c < 32; ++c) den += part[pb + (size_t)c * 4160 + 4096 + d];
  float s = 0.f;
#pragma unroll 8
  for (int c = 0; c < 32; ++c) s += part[pb + (size_t)c * 4160 + (size_t)d * 64 + e];
#pragma unroll
  for (int j = 0; j < 4; ++j) {
    const float ek = __expf(memkv[(h * 4 + j) * 64 + d]);
    den += ek;
    s += ek * memkv[4096 + (h * 4 + j) * 64 + e];
  }
  ctxt[(size_t)bh * 4096 + (size_t)e * 64 + d] = (_Float16)(s / den);
}

// ---------------- kernel 4: out = (P @ ctx)/s, register-direct MFMA ------
// grid (128 l-chunks, 16 heads). No LDS, no barriers. (r3-verified structure)
__global__ __launch_bounds__(256) void attn_out(const _Float16* __restrict__ P,
                                                const _Float16* __restrict__ ctxt,
                                                const int* __restrict__ mask,
                                                float* __restrict__ out) {
  const int l0 = blockIdx.x * 128;
  const int h = blockIdx.y;
  const int bh = (l0 >> 12) * 16 + h;
  const int tid = threadIdx.x;
  const int lane = tid & 63, wid = tid >> 6;
  const int l15 = lane & 15, quad = lane >> 4;

  h8 af[2][2], bf[2][4], bones;
  {
    const _Float16 o1 = (l15 == 0) ? (_Float16)1.f : (_Float16)0.f;
#pragma unroll
    for (int j = 0; j < 8; ++j) bones[j] = o1;
  }
#pragma unroll
  for (int i = 0; i < 2; ++i)
#pragma unroll
    for (int ks = 0; ks < 2; ++ks)
      af[i][ks] = *(const h8*)&P[(size_t)(l0 + wid * 32 + i * 16 + l15) * 1024 +
                                 h * 64 + ks * 32 + quad * 8];
#pragma unroll
  for (int ks = 0; ks < 2; ++ks)
#pragma unroll
    for (int et = 0; et < 4; ++et)
      bf[ks][et] = *(const h8*)&ctxt[(size_t)bh * 4096 +
                                     (size_t)(et * 16 + l15) * 64 + ks * 32 + quad * 8];

  const f4 z = {0.f, 0.f, 0.f, 0.f};
  f4 acc[2][5];
#pragma unroll
  for (int i = 0; i < 2; ++i)
#pragma unroll
    for (int j = 0; j < 5; ++j) acc[i][j] = z;
#pragma unroll
  for (int i = 0; i < 2; ++i)
#pragma unroll
    for (int ks = 0; ks < 2; ++ks) {
#pragma unroll
      for (int et = 0; et < 4; ++et)
        acc[i][et] = __builtin_amdgcn_mfma_f32_16x16x32_f16(af[i][ks], bf[ks][et], acc[i][et], 0, 0, 0);
      acc[i][4] = __builtin_amdgcn_mfma_f32_16x16x32_f16(af[i][ks], bones, acc[i][4], 0, 0, 0);
    }

#pragma unroll
  for (int i = 0; i < 2; ++i) {
#pragma unroll
    for (int r = 0; r < 4; ++r) {
      const int row = l0 + wid * 32 + i * 16 + quad * 4 + r;
      const float sb = __shfl(acc[i][4][r], lane & 48);  // den from col-0 lane
      const float iv = mask[row] ? 1.0f / sb : 0.0f;
#pragma unroll
      for (int et = 0; et < 4; ++et)
        out[(size_t)row * 1024 + h * 64 + et * 16 + l15] = acc[i][et][r] * iv;
    }
  }
}

// ---------------- launch ----------------
extern "C" void kernel_launch(void* const* d_in, const int* in_sizes, int n_in,
                              void* d_out, int out_size, void* d_ws, size_t ws_size,
                              hipStream_t stream) {
  const float* x = (const float*)d_in[0];      // 16777216
  const float* w = (const float*)d_in[1];      // 3145728
  const float* memkv = (const float*)d_in[2];  // 8192
  const int* mask = (const int*)d_in[3];       // 16384
  float* out = (float*)d_out;

  char* ws = (char*)d_ws;
  _Float16* xh   = (_Float16*)(ws + 0);           //  33,554,432
  _Float16* wh   = (_Float16*)(ws + 33554432);    //   6,291,456 (permuted)
  _Float16* P    = (_Float16*)(ws + 39845888);    //  33,554,432
  float*    part = (float*)(ws + 73400320);       //  34,078,720
  _Float16* ctxt = (_Float16*)(ws + 107479040);   //     524,288  (~103 MB)

  cvt_f16<<<dim3(19456), dim3(256), 0, stream>>>((const float4*)x, (const float4*)w,
                                                 (h4*)xh, (h4*)wh);
  gemm_fused<<<dim3(24, 128), dim3(256), 0, stream>>>(xh, wh, mask, P, part);
  reduce_ctx<<<dim3(64, 16), dim3(256), 0, stream>>>(part, memkv, ctxt);
  attn_out<<<dim3(128, 16), dim3(256), 0, stream>>>(P, ctxt, mask, out);
}

// Round 8
// 265.501 us; speedup vs baseline: 1.1247x; 1.1247x over previous
//
#include <hip/hip_runtime.h>

typedef _Float16 h8 __attribute__((ext_vector_type(8)));
typedef _Float16 h4 __attribute__((ext_vector_type(4)));
typedef float f4 __attribute__((ext_vector_type(4)));

typedef __attribute__((address_space(1))) const void GV;
typedef __attribute__((address_space(3))) void SV;

__device__ __forceinline__ void async16(const void* g, void* s) {
  __builtin_amdgcn_global_load_lds((GV*)g, (SV*)s, 16, 0, 0);
}

// x: (4,4096,1024) fp32; w_qkv: (3072,1024) fp32 rows e=h*192+d*3+t;
// mem_kv: (2,16,4,64) fp32; mask: (4,4096) int32; out: (4,4096,1024) fp32.
//
// xh/wh are stored BANK-SWIZZLED: within each 128-B window of a row, the
// eight 16-B chunks are permuted by ch ^= (row & 7). async16 staging lands
// this image in LDS verbatim -> ds_read_b128 fragment loads at BK=64
// (128-B row stride) hit all 32 banks (2-way max = free).
// wh rows are also PERMUTED: [0,2048) = [h][k:64|v:64], [2048,3072) = [h][q:64].
// kv n-tiles fuse ctx in the epilogue (EK/V never hit HBM); q-tiles store
// P n-major (no write amplification; P = attn A-frag layout directly).

#define XC 2097152   // x h8-chunks (16777216/8)
#define WC 393216    // w h8-chunks (3145728/8)

// ---------------- kernel 1: fp32 -> f16 convert; swizzle + W permute -----
__global__ __launch_bounds__(256) void cvt_f16(const float4* __restrict__ x,
                                               const float4* __restrict__ w,
                                               h8* __restrict__ xh,
                                               h8* __restrict__ wh) {
  int t = blockIdx.x * 256 + threadIdx.x;
  if (t < XC) {
    const int row = t >> 7, c7 = t & 127;
    const int dst = (row << 7) | (c7 & 120) | ((c7 & 7) ^ (row & 7));
    float4 a = x[t * 2], b = x[t * 2 + 1];
    h8 o = {(_Float16)a.x, (_Float16)a.y, (_Float16)a.z, (_Float16)a.w,
            (_Float16)b.x, (_Float16)b.y, (_Float16)b.z, (_Float16)b.w};
    xh[dst] = o;
  } else {
    const int u = t - XC;  // 0..393215
    const int rp = u >> 7, c7 = u & 127;
    int sr;
    if (rp < 2048) {
      int h = rp >> 7, c = rp & 127;
      sr = h * 192 + ((c < 64) ? (c * 3 + 1) : ((c - 64) * 3 + 2));
    } else {
      int q = rp - 2048;
      sr = (q >> 6) * 192 + (q & 63) * 3;
    }
    const int dst = (rp << 7) | (c7 & 120) | ((c7 & 7) ^ (rp & 7));
    float4 a = w[sr * 256 + c7 * 2], b = w[sr * 256 + c7 * 2 + 1];
    h8 o = {(_Float16)a.x, (_Float16)a.y, (_Float16)a.z, (_Float16)a.w,
            (_Float16)b.x, (_Float16)b.y, (_Float16)b.z, (_Float16)b.w};
    wh[dst] = o;
  }
}

// ---------------- kernel 2: fused qkv GEMM + ctx-partial / P epilogue ----
// grid (24 n-tiles, 128 m-tiles). bx<16: kv-tile (head bx). bx>=16: q-tile.
// BK=64, conflict-free swizzled LDS. part per (bh, m-chunk): 4096+64 floats.
__global__ __launch_bounds__(256, 3) void gemm_fused(const _Float16* __restrict__ A,
                                                     const _Float16* __restrict__ W,
                                                     const int* __restrict__ mask,
                                                     _Float16* __restrict__ P,
                                                     float* __restrict__ part) {
  __shared__ _Float16 smem[128 * 128];  // 32 KB: As 16K + Bs 16K; epi reuse
  _Float16* const As = smem;
  _Float16* const Bs = smem + 8192;
  const int tid = threadIdx.x;
  const int lane = tid & 63, wid = tid >> 6;
  const int wm = wid & 1, wn = wid >> 1;
  const int l15 = lane & 15, quad = lane >> 4;
  const int m0 = blockIdx.y * 128;
  const int n0 = blockIdx.x * 128;

  const f4 z = {0.f, 0.f, 0.f, 0.f};
  f4 acc[4][4];
#pragma unroll
  for (int i = 0; i < 4; ++i)
#pragma unroll
    for (int j = 0; j < 4; ++j) acc[i][j] = z;

  const int swz = l15 & 7;  // row&7 for all fragment rows (offsets are mult of 8)

  for (int kt = 0; kt < 16; ++kt) {
    const int k0 = kt * 64;
#pragma unroll
    for (int it = 0; it < 4; ++it) {
      const int idx = it * 256 + tid;     // 0..1023: row=idx>>3, cg=idx&7
      const int row = idx >> 3, cg = idx & 7;
      async16(A + ((size_t)(m0 + row) * 1024 + k0 + cg * 8), As + idx * 8);
      async16(W + ((size_t)(n0 + row) * 1024 + k0 + cg * 8), Bs + idx * 8);
    }
    __syncthreads();
#pragma unroll
    for (int ks = 0; ks < 2; ++ks) {
      const int pc = ((ks << 2) | quad) ^ swz;  // swizzled chunk within row
      h8 af[4], bf[4];
#pragma unroll
      for (int i = 0; i < 4; ++i)
        af[i] = *(const h8*)&As[(wm * 64 + i * 16 + l15) * 64 + pc * 8];
#pragma unroll
      for (int j = 0; j < 4; ++j)
        bf[j] = *(const h8*)&Bs[(wn * 64 + j * 16 + l15) * 64 + pc * 8];
#pragma unroll
      for (int i = 0; i < 4; ++i)
#pragma unroll
        for (int j = 0; j < 4; ++j)
          acc[i][j] = __builtin_amdgcn_mfma_f32_16x16x32_f16(af[i], bf[j], acc[i][j], 0, 0, 0);
    }
    __syncthreads();
  }

  if (n0 < 2048) {
    // ---- kv epilogue: exp(k)+mask, LDS round-trip, ctx partial via MFMA --
    const int h = n0 >> 7;
    const int b = m0 >> 12;
    const int lc = (m0 & 4095) >> 7;     // m-chunk within batch, 0..31
    const int bh = b * 16 + h;
    // write ek (cols 0..63) / v (cols 64..127) into XOR-swizzled LDS [c][128n]
#pragma unroll
    for (int i = 0; i < 4; ++i) {
      const int nb = wm * 64 + i * 16 + quad * 4;
#pragma unroll
      for (int j = 0; j < 4; ++j) {
        const int c = wn * 64 + j * 16 + l15;
        h4 o;
        if (wn == 0) {
#pragma unroll
          for (int r = 0; r < 4; ++r)
            o[r] = (_Float16)(mask[m0 + nb + r] ? __expf(acc[i][j][r]) : 0.f);
        } else {
#pragma unroll
          for (int r = 0; r < 4; ++r) o[r] = (_Float16)acc[i][j][r];
        }
        *(h4*)&smem[c * 128 + (nb ^ (l15 * 8))] = o;
      }
    }
    __syncthreads();
    // ctx[d][e] = sum_n ek[n][d] v[n][e]; wave w owns d-stripe [16w,16w+16)
    f4 cacc[5];
#pragma unroll
    for (int i = 0; i < 5; ++i) cacc[i] = z;
    h8 bones;
    {
      const _Float16 o1 = (l15 == 0) ? (_Float16)1.f : (_Float16)0.f;
#pragma unroll
      for (int j = 0; j < 8; ++j) bones[j] = o1;
    }
    const int ds = wid * 16;
#pragma unroll
    for (int ks = 0; ks < 4; ++ks) {
      const int nb2 = (ks * 32 + quad * 8) ^ (l15 * 8);
      h8 a = *(const h8*)&smem[(ds + l15) * 128 + nb2];
#pragma unroll
      for (int et = 0; et < 4; ++et) {
        h8 bv = *(const h8*)&smem[(64 + et * 16 + l15) * 128 + nb2];
        cacc[et] = __builtin_amdgcn_mfma_f32_16x16x32_f16(a, bv, cacc[et], 0, 0, 0);
      }
      cacc[4] = __builtin_amdgcn_mfma_f32_16x16x32_f16(a, bones, cacc[4], 0, 0, 0);
    }
    const size_t pb = ((size_t)bh * 32 + lc) * 4160;
    const int dw = ds + quad * 4;
#pragma unroll
    for (int et = 0; et < 4; ++et)
#pragma unroll
      for (int r = 0; r < 4; ++r)
        part[pb + (size_t)(dw + r) * 64 + et * 16 + l15] = cacc[et][r];
    if (l15 == 0) {
#pragma unroll
      for (int r = 0; r < 4; ++r) part[pb + 4096 + dw + r] = cacc[4][r];
    }
  } else {
    // ---- q epilogue: P = exp(q/8), n-major scalar stores (no write amp) --
#pragma unroll
    for (int i = 0; i < 4; ++i) {
      const int rg = m0 + wm * 64 + i * 16 + quad * 4;
#pragma unroll
      for (int j = 0; j < 4; ++j) {
        const int qc = (n0 - 2048) + wn * 64 + j * 16 + l15;  // = h*64+d
#pragma unroll
        for (int r = 0; r < 4; ++r)
          P[(size_t)(rg + r) * 1024 + qc] = (_Float16)__expf(acc[i][j][r] * 0.125f);
      }
    }
  }
}

// ---------------- kernel 3: reduce partials + memkv, store ctx^T ---------
// grid (64 bh, 16 d-slices). Thread (dl = tid>>6, e = tid&63) owns one (d,e).
__global__ __launch_bounds__(256) void reduce_ctx(const float* __restrict__ part,
                                                  const float* __restrict__ memkv,
                                                  _Float16* __restrict__ ctxt) {
  const int bh = blockIdx.x;
  const int dsl = blockIdx.y;
  const int h = bh & 15;
  const int tid = threadIdx.x;
  const int dl = tid >> 6, e = tid & 63;
  const int d = dsl * 4 + dl;
  const size_t pb = (size_t)bh * 32 * 4160;

  float den = 0.f;
#pragma unroll 8
  for (int c = 0; c < 32; ++c) den += part[pb + (size_t)c * 4160 + 4096 + d];
  float s = 0.f;
#pragma unroll 8
  for (int c = 0; c < 32; ++c) s += part[pb + (size_t)c * 4160 + (size_t)d * 64 + e];
#pragma unroll
  for (int j = 0; j < 4; ++j) {
    const float ek = __expf(memkv[(h * 4 + j) * 64 + d]);
    den += ek;
    s += ek * memkv[4096 + (h * 4 + j) * 64 + e];
  }
  ctxt[(size_t)bh * 4096 + (size_t)e * 64 + d] = (_Float16)(s / den);
}

// ---------------- kernel 4: out = (P @ ctx)/s, register-direct MFMA ------
// grid (128 l-chunks, 16 heads). No LDS, no barriers.
__global__ __launch_bounds__(256) void attn_out(const _Float16* __restrict__ P,
                                                const _Float16* __restrict__ ctxt,
                                                const int* __restrict__ mask,
                                                float* __restrict__ out) {
  const int l0 = blockIdx.x * 128;
  const int h = blockIdx.y;
  const int bh = (l0 >> 12) * 16 + h;
  const int tid = threadIdx.x;
  const int lane = tid & 63, wid = tid >> 6;
  const int l15 = lane & 15, quad = lane >> 4;

  h8 af[2][2], bf[2][4], bones;
  {
    const _Float16 o1 = (l15 == 0) ? (_Float16)1.f : (_Float16)0.f;
#pragma unroll
    for (int j = 0; j < 8; ++j) bones[j] = o1;
  }
#pragma unroll
  for (int i = 0; i < 2; ++i)
#pragma unroll
    for (int ks = 0; ks < 2; ++ks)
      af[i][ks] = *(const h8*)&P[(size_t)(l0 + wid * 32 + i * 16 + l15) * 1024 +
                                 h * 64 + ks * 32 + quad * 8];
#pragma unroll
  for (int ks = 0; ks < 2; ++ks)
#pragma unroll
    for (int et = 0; et < 4; ++et)
      bf[ks][et] = *(const h8*)&ctxt[(size_t)bh * 4096 +
                                     (size_t)(et * 16 + l15) * 64 + ks * 32 + quad * 8];

  const f4 z = {0.f, 0.f, 0.f, 0.f};
  f4 acc[2][5];
#pragma unroll
  for (int i = 0; i < 2; ++i)
#pragma unroll
    for (int j = 0; j < 5; ++j) acc[i][j] = z;
#pragma unroll
  for (int i = 0; i < 2; ++i)
#pragma unroll
    for (int ks = 0; ks < 2; ++ks) {
#pragma unroll
      for (int et = 0; et < 4; ++et)
        acc[i][et] = __builtin_amdgcn_mfma_f32_16x16x32_f16(af[i][ks], bf[ks][et], acc[i][et], 0, 0, 0);
      acc[i][4] = __builtin_amdgcn_mfma_f32_16x16x32_f16(af[i][ks], bones, acc[i][4], 0, 0, 0);
    }

#pragma unroll
  for (int i = 0; i < 2; ++i) {
#pragma unroll
    for (int r = 0; r < 4; ++r) {
      const int row = l0 + wid * 32 + i * 16 + quad * 4 + r;
      const float sb = __shfl(acc[i][4][r], lane & 48);  // den from col-0 lane
      const float iv = mask[row] ? 1.0f / sb : 0.0f;
#pragma unroll
      for (int et = 0; et < 4; ++et)
        out[(size_t)row * 1024 + h * 64 + et * 16 + l15] = acc[i][et][r] * iv;
    }
  }
}

// ---------------- launch ----------------
extern "C" void kernel_launch(void* const* d_in, const int* in_sizes, int n_in,
                              void* d_out, int out_size, void* d_ws, size_t ws_size,
                              hipStream_t stream) {
  const float* x = (const float*)d_in[0];      // 16777216
  const float* w = (const float*)d_in[1];      // 3145728
  const float* memkv = (const float*)d_in[2];  // 8192
  const int* mask = (const int*)d_in[3];       // 16384
  float* out = (float*)d_out;

  char* ws = (char*)d_ws;
  _Float16* xh   = (_Float16*)(ws + 0);           //  33,554,432 (swizzled)
  _Float16* wh   = (_Float16*)(ws + 33554432);    //   6,291,456 (permuted+swizzled)
  _Float16* P    = (_Float16*)(ws + 39845888);    //  33,554,432
  float*    part = (float*)(ws + 73400320);       //  34,078,720
  _Float16* ctxt = (_Float16*)(ws + 107479040);   //     524,288  (~103 MB)

  cvt_f16<<<dim3(9728), dim3(256), 0, stream>>>((const float4*)x, (const float4*)w,
                                                (h8*)xh, (h8*)wh);
  gemm_fused<<<dim3(24, 128), dim3(256), 0, stream>>>(xh, wh, mask, P, part);
  reduce_ctx<<<dim3(64, 16), dim3(256), 0, stream>>>(part, memkv, ctxt);
  attn_out<<<dim3(128, 16), dim3(256), 0, stream>>>(P, ctxt, mask, out);
}